// Round 15
// baseline (274.323 us; speedup 1.0000x reference)
//
#include <hip/hip_runtime.h>
#include <cstdint>
#include <cstddef>

#define BB 256
#define TT 128
#define AA 4
#define II 128
#define HH 256
#define K3 768  // 3*H

typedef __attribute__((ext_vector_type(8))) short short8;
typedef __attribute__((ext_vector_type(4))) float f32x4;
typedef __attribute__((ext_vector_type(4))) unsigned short ushort4_t;

// workgroup barrier draining ONLY lgkmcnt (LDS), not vmcnt.
#define LGKM_BARRIER() asm volatile("s_waitcnt lgkmcnt(0)\n\ts_barrier" ::: "memory")

static __device__ __forceinline__ unsigned short f2bf(float f) {
  unsigned int b = __float_as_uint(f);
  return (unsigned short)((b + 0x7FFFu + ((b >> 16) & 1u)) >> 16);  // RNE
}
static __device__ __forceinline__ float bf2f(unsigned short u) {
  return __uint_as_float(((unsigned int)u) << 16);
}

// fp32 -> bf16 weight conversion (FALLBACK PATH ONLY)
__global__ void wconv_kernel(const float* __restrict__ wih,
                             const float* __restrict__ whh,
                             unsigned short* __restrict__ o) {
  int i = blockIdx.x * 512 + threadIdx.x;
  float v = (i < K3 * II) ? wih[i] : whh[i - K3 * II];
  o[i] = f2bf(v);
}

// ---------------- Phase A: gi = x * W_ih^T + b_ih (+ b_hh for r,z), bf16 ----
// v4: wconv folded in. W_ih converted inline from fp32 (one-time per block,
// persistent wf regs). Blocks 0..383 also convert a 512-el slice of W_hh
// bf16 into the workspace (rnn reads it after gi completes; layout same).
__global__ __launch_bounds__(512, 4) void gi_kernel(
    const float* __restrict__ x,
    const float* __restrict__ bih_g,
    const float* __restrict__ bhh_g,
    const float* __restrict__ wih_f,
    const float* __restrict__ whh_f,
    unsigned short* __restrict__ wb,         // ws base: [W_ih(dead) | W_hh]
    unsigned short* __restrict__ gi) {
  __shared__ alignas(16) unsigned short xs[64][144];
  __shared__ alignas(16) unsigned short gst[16][408];
  __shared__ float bihs[384];

  const int tid = threadIdx.x;
  const int l = tid & 63, w = tid >> 6;
  const int c = l & 15, g = l >> 4;
  const int bid = blockIdx.x;
  const size_t m0 = (size_t)(bid >> 1) * 64;
  const int gh0 = (bid & 1) * 384;  // gate-half offset

  // side job: W_hh fp32 -> bf16 (384 blocks x 512 els = 196608 = K3*HH)
  if (bid < 384) {
    int idx = bid * 512 + tid;
    wb[K3 * II + idx] = f2bf(whh_f[idx]);
  }

  for (int i = tid; i < 384; i += 512) {
    int gg = gh0 + i;
    bihs[i] = bih_g[gg] + (gg < 2 * HH ? bhh_g[gg] : 0.f);
  }
  for (int i = tid; i < 64 * 128; i += 512) {
    int row = i >> 7, col = i & 127;
    xs[row][col] = f2bf(x[m0 * 128 + i]);
  }
  // persistent W_ih fragments (inline fp32->bf16, one-time)
  short8 wf[3][4];
#pragma unroll
  for (int kt = 0; kt < 3; ++kt) {
    int row = gh0 + 48 * w + kt * 16 + c;
#pragma unroll
    for (int kk = 0; kk < 4; ++kk) {
      const float* p = &wih_f[(size_t)row * II + kk * 32 + g * 8];
#pragma unroll
      for (int e = 0; e < 8; ++e) wf[kt][kk][e] = (short)f2bf(p[e]);
    }
  }
  LGKM_BARRIER();

  for (int chunk = 0; chunk < 4; ++chunk) {
    short8 bx[4];
#pragma unroll
    for (int kk = 0; kk < 4; ++kk)
      bx[kk] = *(const short8*)&xs[chunk * 16 + c][kk * 32 + g * 8];
    f32x4 acc[3];
#pragma unroll
    for (int kt = 0; kt < 3; ++kt) acc[kt] = (f32x4){0.f, 0.f, 0.f, 0.f};
#pragma unroll
    for (int kt = 0; kt < 3; ++kt)
#pragma unroll
      for (int kk = 0; kk < 4; ++kk)
        acc[kt] = __builtin_amdgcn_mfma_f32_16x16x32_bf16(wf[kt][kk], bx[kk], acc[kt], 0, 0, 0);
#pragma unroll
    for (int kt = 0; kt < 3; ++kt) {
      int gate0 = 48 * w + kt * 16 + g * 4;  // local within half
      ushort4_t p;
#pragma unroll
      for (int r = 0; r < 4; ++r) p[r] = f2bf(acc[kt][r] + bihs[gate0 + r]);
      *(ushort4_t*)&gst[c][gate0] = p;
    }
    LGKM_BARRIER();
    for (int i = tid; i < 16 * 48; i += 512) {
      int row = i / 48, seg = i - row * 48;
      *(short8*)(gi + (m0 + chunk * 16 + row) * K3 + gh0 + seg * 8) =
          *(const short8*)&gst[row][seg * 8];
    }
    LGKM_BARRIER();
  }
}

// ---------------- Phase B: chunk-parallel recurrence (16 MFMA columns) -----
// Byte-identical STEP/layouts to verified round 14. Only change: odd-maxlen
// epilogue (no round-up-to-even wasted step).
__global__ __launch_bounds__(512, 2) void rnn_kernel(
    const void* __restrict__ init_raw,
    const float* __restrict__ bhh_g,
    const unsigned short* __restrict__ wsb,  // ws bf16 base: [W_ih | W_hh]
    const unsigned short* __restrict__ gi,
    float* __restrict__ out) {
  extern __shared__ char smem[];
  unsigned short* wlN = (unsigned short*)smem;              // 131072 B (N frags)
  unsigned short* hflat = (unsigned short*)(smem + 131072); // 2 x 4096 ushorts
  unsigned char* mskL = (unsigned char*)(smem + 147456);    // 132 B
  int* bnd = (int*)(smem + 147592);                         // 5 ints
  int* detf = (int*)(smem + 147612);                        // 3 ints

  const int tid = threadIdx.x;
  const int b = blockIdx.x;
  const unsigned short* whh_b = wsb + K3 * II;
  const int l = tid & 63, w = tid >> 6;
  const int c = l & 15, g = l >> 4;

  if (tid < 3) detf[tid] = 0;

  // ---- persistent weight tiles FIRST (latency overlaps probe below) ----
  short8 wreg[4][8];
#pragma unroll
  for (int q = 0; q < 4; ++q) {
    int row = (q >> 1) * 256 + 32 * w + (q & 1) * 16 + c;
#pragma unroll
    for (int kk = 0; kk < 8; ++kk)
      wreg[q][kk] = *(const short8*)&whh_b[(size_t)row * HH + kk * 32 + g * 8];
  }
  // N0,N1 tiles -> LDS fragment order (verified layout)
  for (int f = tid; f < 8192; f += 512) {
    int w2 = f >> 10, n = (f >> 9) & 1, kk = (f >> 6) & 7, l2 = f & 63;
    int row = 512 + 32 * w2 + 16 * n + (l2 & 15);
    int col = kk * 32 + (l2 >> 4) * 8;
    *(short8*)(wlN + (size_t)f * 8) = *(const short8*)&whh_b[(size_t)row * HH + col];
  }
  for (int i = tid; i < 8192; i += 512) hflat[i] = 0;

  // ---- is_init layout probe (verified r1-r14 logic) ----
  {
    const unsigned int* wq = (const unsigned int*)init_raw;
    int notf = 0, gt1 = 0, oddnz = 0;
    for (int i = tid; i < (BB * TT / 4); i += 512) {
      unsigned int v = wq[i];
      notf |= (v != 0u && v != 0x3F800000u);
      gt1 |= (v > 1u);
      if (i & 1) oddnz |= (v != 0u);
    }
    if (notf) atomicOr(&detf[0], 1);
    if (gt1) atomicOr(&detf[1], 1);
    if (oddnz) atomicOr(&detf[2], 1);
  }
  __syncthreads();
  if (tid < TT) {
    int layout = (!detf[0]) ? 1 : (detf[1] ? 0 : (detf[2] ? 1 : 2));
    int e = b * TT + tid;
    unsigned int v;
    if (layout == 0)      v = ((const unsigned char*)init_raw)[e];
    else if (layout == 1) v = ((const unsigned int*)init_raw)[e];
    else                  v = ((const unsigned int*)init_raw)[2 * e];
    mskL[tid] = v ? 1 : 0;
  }
  if (tid == TT) mskL[TT] = 1;  // sentinel: t=128 "resets"
  __syncthreads();
  // chunk boundaries: b_q = first reset >= 32q (else 128)
  if (tid < 3) {
    int target = 32 * (tid + 1);
    int bb = TT;
    for (int t = target; t < TT; ++t)
      if (mskL[t]) { bb = t; break; }
    bnd[tid + 1] = bb;
  }
  if (tid == 3) { bnd[0] = 0; bnd[4] = TT; }
  __syncthreads();

  // per-lane column: chunk q = c>>2, agent a = c&3; units j0 = 32w+4g (+16)
  const int a = c & 3, q = c >> 2;
  const int j0 = 32 * w + g * 4;
  int tcur = bnd[q];
  int trem = bnd[q + 1] - tcur;
  int maxlen = bnd[1] - bnd[0];
  { int l1 = bnd[2] - bnd[1]; if (l1 > maxlen) maxlen = l1;
    int l2 = bnd[3] - bnd[2]; if (l2 > maxlen) maxlen = l2;
    int l3 = TT - bnd[3];     if (l3 > maxlen) maxlen = l3; }
  const int taddr = (tcur < TT) ? tcur : (TT - 1);
  const unsigned short* gp = gi + ((size_t)(b * TT + taddr) * AA + a) * K3 + j0;
  float* op = out + ((size_t)(b * TT + taddr) * AA + a) * HH + j0;
  f32x4 bn[2];
  bn[0] = *(const f32x4*)&bhh_g[2 * HH + j0];
  bn[1] = *(const f32x4*)&bhh_g[2 * HH + j0 + 16];
  float* hnp = out + (size_t)BB * TT * AA * HH + ((size_t)b * AA + a) * HH + j0;

  // hsb addressing: READ slot = kk*512 + l*8 (lane-contig 16B, conflict-free)
  // WRITE: w*512 + (g>>1)*128 + c*8 + (g&1)*4, hb1 at +256.
  const unsigned short* hrd = hflat + l * 8;                       // +P*4096+kk*512
  unsigned short* hw1 = hflat + w * 512 + (g >> 1) * 128 + c * 8 + (g & 1) * 4;
  const unsigned short* wlp = wlN + w * 8192 + l * 8;              // +n*4096+kk*512

  f32x4 hold[2];
  hold[0] = (f32x4){0.f, 0.f, 0.f, 0.f};
  hold[1] = (f32x4){0.f, 0.f, 0.f, 0.f};
  const f32x4 Z4 = {0.f, 0.f, 0.f, 0.f};

#define L2E 1.44269504088896f

#define STEP(P)                                                                   \
  do {                                                                            \
    ushort4_t gr0 = *(const ushort4_t*)(gp);                                      \
    ushort4_t gr1 = *(const ushort4_t*)(gp + 16);                                 \
    ushort4_t gz0 = *(const ushort4_t*)(gp + 256);                                \
    ushort4_t gz1 = *(const ushort4_t*)(gp + 272);                                \
    ushort4_t gn0 = *(const ushort4_t*)(gp + 512);                                \
    ushort4_t gn1 = *(const ushort4_t*)(gp + 528);                                \
    short8 bhf[8];                                                                \
    _Pragma("unroll") for (int kk = 0; kk < 8; ++kk)                              \
        bhf[kk] = *(const short8*)(hrd + (P) * 4096 + kk * 512);                  \
    f32x4 aR0 = __builtin_amdgcn_mfma_f32_16x16x32_bf16(wreg[0][0], bhf[0], Z4, 0, 0, 0); \
    f32x4 aR1 = __builtin_amdgcn_mfma_f32_16x16x32_bf16(wreg[1][0], bhf[0], Z4, 0, 0, 0); \
    f32x4 aZ0 = __builtin_amdgcn_mfma_f32_16x16x32_bf16(wreg[2][0], bhf[0], Z4, 0, 0, 0); \
    f32x4 aZ1 = __builtin_amdgcn_mfma_f32_16x16x32_bf16(wreg[3][0], bhf[0], Z4, 0, 0, 0); \
    f32x4 aN0 = __builtin_amdgcn_mfma_f32_16x16x32_bf16(*(const short8*)(wlp), bhf[0], Z4, 0, 0, 0); \
    f32x4 aN1 = __builtin_amdgcn_mfma_f32_16x16x32_bf16(*(const short8*)(wlp + 4096), bhf[0], Z4, 0, 0, 0); \
    _Pragma("unroll") for (int kk = 1; kk < 8; ++kk) {                            \
      aR0 = __builtin_amdgcn_mfma_f32_16x16x32_bf16(wreg[0][kk], bhf[kk], aR0, 0, 0, 0); \
      aR1 = __builtin_amdgcn_mfma_f32_16x16x32_bf16(wreg[1][kk], bhf[kk], aR1, 0, 0, 0); \
      aZ0 = __builtin_amdgcn_mfma_f32_16x16x32_bf16(wreg[2][kk], bhf[kk], aZ0, 0, 0, 0); \
      aZ1 = __builtin_amdgcn_mfma_f32_16x16x32_bf16(wreg[3][kk], bhf[kk], aZ1, 0, 0, 0); \
      aN0 = __builtin_amdgcn_mfma_f32_16x16x32_bf16(*(const short8*)(wlp + kk * 512), bhf[kk], aN0, 0, 0, 0); \
      aN1 = __builtin_amdgcn_mfma_f32_16x16x32_bf16(*(const short8*)(wlp + 4096 + kk * 512), bhf[kk], aN1, 0, 0, 0); \
    }                                                                             \
    f32x4 hnv0, hnv1;                                                             \
    ushort4_t hb0, hb1;                                                           \
    _Pragma("unroll") for (int r = 0; r < 4; ++r) {                               \
      const float pr = bf2f(gr0[r]) + aR0[r];                                     \
      const float pz = bf2f(gz0[r]) + aZ0[r];                                     \
      const float rs = __builtin_amdgcn_rcpf(1.f + __builtin_amdgcn_exp2f(-pr * L2E)); \
      const float zs = __builtin_amdgcn_rcpf(1.f + __builtin_amdgcn_exp2f(-pz * L2E)); \
      const float hn = aN0[r] + bn[0][r];                                         \
      const float pre = bf2f(gn0[r]) + rs * hn;                                   \
      const float nn = 1.f - 2.f * __builtin_amdgcn_rcpf(1.f + __builtin_amdgcn_exp2f(pre * (2.f * L2E))); \
      const float hv = fmaf(zs, hold[0][r] - nn, nn);                             \
      hnv0[r] = hv; hb0[r] = f2bf(hv);                                            \
    }                                                                             \
    _Pragma("unroll") for (int r = 0; r < 4; ++r) {                               \
      const float pr = bf2f(gr1[r]) + aR1[r];                                     \
      const float pz = bf2f(gz1[r]) + aZ1[r];                                     \
      const float rs = __builtin_amdgcn_rcpf(1.f + __builtin_amdgcn_exp2f(-pr * L2E)); \
      const float zs = __builtin_amdgcn_rcpf(1.f + __builtin_amdgcn_exp2f(-pz * L2E)); \
      const float hn = aN1[r] + bn[1][r];                                         \
      const float pre = bf2f(gn1[r]) + rs * hn;                                   \
      const float nn = 1.f - 2.f * __builtin_amdgcn_rcpf(1.f + __builtin_amdgcn_exp2f(pre * (2.f * L2E))); \
      const float hv = fmaf(zs, hold[1][r] - nn, nn);                             \
      hnv1[r] = hv; hb1[r] = f2bf(hv);                                            \
    }                                                                             \
    hold[0] = hnv0; hold[1] = hnv1;                                               \
    const bool active = (trem > 0);                                               \
    if (active) {                                                                 \
      *(f32x4*)op = hnv0;                                                         \
      *(f32x4*)(op + 16) = hnv1;                                                  \
      if (tcur == TT - 1) { *(f32x4*)hnp = hnv0; *(f32x4*)(hnp + 16) = hnv1; }    \
      tcur += 1; trem -= 1;                                                       \
      if (trem > 0) { gp += AA * K3; op += AA * HH; }                             \
    }                                                                             \
    const int mn = mskL[tcur];                                                    \
    if (mn) {                                                                     \
      hb0 = (ushort4_t)0; hb1 = (ushort4_t)0;                                     \
      hold[0] = Z4; hold[1] = Z4;                                                 \
    }                                                                             \
    *(ushort4_t*)(hw1 + (1 - (P)) * 4096) = hb0;                                  \
    *(ushort4_t*)(hw1 + 256 + (1 - (P)) * 4096) = hb1;                            \
    LGKM_BARRIER();                                                               \
  } while (0)

  const int pairs = maxlen >> 1;
  for (int i = 0; i < pairs; ++i) {
    STEP(0);
    STEP(1);
  }
  if (maxlen & 1) STEP(0);
#undef STEP
}

// ---------------- Fallback: round-1 kernel (known-pass) ----------------
template <int WSW>
__global__ __launch_bounds__(512, 2) void gru_kernel(
    const float* __restrict__ x,
    const void* __restrict__ init_raw,
    const float* __restrict__ wih_f,
    const float* __restrict__ whh_f,
    const float* __restrict__ bih_g,
    const float* __restrict__ bhh_g,
    const unsigned short* __restrict__ wb,
    float* __restrict__ out) {
  __shared__ alignas(16) unsigned short xs[AA][II + 8];
  __shared__ alignas(16) unsigned short hsb[AA][HH + 8];
  __shared__ float hs32[AA][HH];
  __shared__ float gi_s[K3][5];
  __shared__ float gh_s[K3][5];
  __shared__ float bihs[K3];
  __shared__ float bhhs[K3];
  __shared__ unsigned char msk[TT];
  __shared__ int detf[3];

  const int tid = threadIdx.x;
  const int b = blockIdx.x;

  if (tid < 3) detf[tid] = 0;
  for (int i = tid; i < K3; i += 512) { bihs[i] = bih_g[i]; bhhs[i] = bhh_g[i]; }
  for (int i = tid; i < AA * HH; i += 512) {
    hs32[i >> 8][i & 255] = 0.f;
    hsb[i >> 8][i & 255] = 0;
  }
  __syncthreads();
  {
    const unsigned int* wq = (const unsigned int*)init_raw;
    int notf = 0, gt1 = 0, oddnz = 0;
    for (int i = tid; i < (BB * TT / 4); i += 512) {
      unsigned int v = wq[i];
      notf |= (v != 0u && v != 0x3F800000u);
      gt1 |= (v > 1u);
      if (i & 1) oddnz |= (v != 0u);
    }
    if (notf) atomicOr(&detf[0], 1);
    if (gt1) atomicOr(&detf[1], 1);
    if (oddnz) atomicOr(&detf[2], 1);
  }
  __syncthreads();
  if (tid < TT) {
    int layout = (!detf[0]) ? 1 : (detf[1] ? 0 : (detf[2] ? 1 : 2));
    int e = b * TT + tid;
    unsigned int v;
    if (layout == 0)      v = ((const unsigned char*)init_raw)[e];
    else if (layout == 1) v = ((const unsigned int*)init_raw)[e];
    else                  v = ((const unsigned int*)init_raw)[2 * e];
    msk[tid] = v ? 1 : 0;
  }
  __syncthreads();

  const int l = tid & 63;
  const int w = tid >> 6;
  const int c = l & 15;
  const int g = l >> 4;
  const bool act = (c < AA);
  const int xa = tid >> 7, xi = tid & 127;
  const float* xrow = x + (size_t)b * TT * AA * II;
  const unsigned short* wihb = wb;
  const unsigned short* whhb = wb + K3 * II;

  for (int t = 0; t < TT; ++t) {
    xs[xa][xi] = f2bf(xrow[(size_t)t * (AA * II) + tid]);
    if (msk[t]) {
      for (int i = tid; i < AA * HH; i += 512) {
        hs32[i >> 8][i & 255] = 0.f;
        hsb[i >> 8][i & 255] = 0;
      }
    }
    __syncthreads();

    short8 bx[4], bh[8];
    if (act) {
#pragma unroll
      for (int kk = 0; kk < 4; ++kk) bx[kk] = *(const short8*)&xs[c][kk * 32 + g * 8];
#pragma unroll
      for (int kk = 0; kk < 8; ++kk) bh[kk] = *(const short8*)&hsb[c][kk * 32 + g * 8];
    } else {
#pragma unroll
      for (int kk = 0; kk < 4; ++kk) bx[kk] = (short8)0;
#pragma unroll
      for (int kk = 0; kk < 8; ++kk) bh[kk] = (short8)0;
    }

#pragma unroll
    for (int kt = 0; kt < 6; ++kt) {
      const int ar = w * 96 + kt * 16 + c;
      f32x4 acc = {0.f, 0.f, 0.f, 0.f};
#pragma unroll
      for (int kk = 0; kk < 4; ++kk) {
        short8 aw;
        if (WSW) {
          aw = *(const short8*)&wihb[(size_t)ar * II + kk * 32 + g * 8];
        } else {
          const float* p = &wih_f[(size_t)ar * II + kk * 32 + g * 8];
#pragma unroll
          for (int e = 0; e < 8; ++e) aw[e] = (short)f2bf(p[e]);
        }
        acc = __builtin_amdgcn_mfma_f32_16x16x32_bf16(aw, bx[kk], acc, 0, 0, 0);
      }
      if (act) {
        const int dr = w * 96 + kt * 16 + g * 4;
#pragma unroll
        for (int r = 0; r < 4; ++r) gi_s[dr + r][c] = acc[r];
      }
    }

#pragma unroll
    for (int kt = 0; kt < 6; ++kt) {
      const int ar = w * 96 + kt * 16 + c;
      f32x4 acc = {0.f, 0.f, 0.f, 0.f};
#pragma unroll
      for (int kk = 0; kk < 8; ++kk) {
        short8 aw;
        if (WSW) {
          aw = *(const short8*)&whhb[(size_t)ar * HH + kk * 32 + g * 8];
        } else {
          const float* p = &whh_f[(size_t)ar * HH + kk * 32 + g * 8];
#pragma unroll
          for (int e = 0; e < 8; ++e) aw[e] = (short)f2bf(p[e]);
        }
        acc = __builtin_amdgcn_mfma_f32_16x16x32_bf16(aw, bh[kk], acc, 0, 0, 0);
      }
      if (act) {
        const int dr = w * 96 + kt * 16 + g * 4;
#pragma unroll
        for (int r = 0; r < 4; ++r) gh_s[dr + r][c] = acc[r];
      }
    }
    __syncthreads();

#pragma unroll
    for (int it = 0; it < 2; ++it) {
      const int idx = it * 512 + tid;
      const int a = idx >> 8, j = idx & 255;
      const float ir = gi_s[j][a] + bihs[j];
      const float iz = gi_s[HH + j][a] + bihs[HH + j];
      const float inn = gi_s[2 * HH + j][a] + bihs[2 * HH + j];
      const float hr = gh_s[j][a] + bhhs[j];
      const float hz = gh_s[HH + j][a] + bhhs[HH + j];
      const float hn = gh_s[2 * HH + j][a] + bhhs[2 * HH + j];
      const float r = 1.f / (1.f + __expf(-(ir + hr)));
      const float z = 1.f / (1.f + __expf(-(iz + hz)));
      const float pre = inn + r * hn;
      const float ea = __expf(-2.f * fabsf(pre));
      float n = (1.f - ea) / (1.f + ea);
      n = (pre < 0.f) ? -n : n;
      const float hold = hs32[a][j];
      const float hnew = (1.f - z) * n + z * hold;
      hs32[a][j] = hnew;
      hsb[a][j] = f2bf(hnew);
      out[(((size_t)b * TT + t) * AA + a) * HH + j] = hnew;
      if (t == TT - 1)
        out[(size_t)BB * TT * AA * HH + ((size_t)b * AA + a) * HH + j] = hnew;
    }
    __syncthreads();
  }
}

extern "C" void kernel_launch(void* const* d_in, const int* in_sizes, int n_in,
                              void* d_out, int out_size, void* d_ws, size_t ws_size,
                              hipStream_t stream) {
  (void)in_sizes; (void)n_in; (void)out_size;
  const float* x = (const float*)d_in[0];
  const void* is_init = d_in[1];
  const float* wih = (const float*)d_in[2];
  const float* whh = (const float*)d_in[3];
  const float* bih = (const float*)d_in[4];
  const float* bhh = (const float*)d_in[5];
  float* out = (float*)d_out;

  const size_t W_ELS = (size_t)(K3 * II + K3 * HH);        // 294,912
  const size_t W_BYTES = W_ELS * 2;                        // 589,824
  const size_t GI_BYTES = (size_t)BB * TT * AA * K3 * 2;   // 201,326,592
  const int SMEM = 147632;

  if (ws_size >= W_BYTES + GI_BYTES) {
    hipError_t e = hipFuncSetAttribute(
        (const void*)rnn_kernel, hipFuncAttributeMaxDynamicSharedMemorySize, SMEM);
    if (e == hipSuccess) {
      unsigned short* wb = (unsigned short*)d_ws;
      unsigned short* gi = wb + W_ELS;
      gi_kernel<<<4096, 512, 0, stream>>>(x, bih, bhh, wih, whh, wb, gi);
      rnn_kernel<<<BB, 512, SMEM, stream>>>(is_init, bhh, wb, gi, out);
      return;
    }
  }
  // fallback (round-1 verified path)
  if (ws_size >= W_BYTES) {
    unsigned short* wb = (unsigned short*)d_ws;
    wconv_kernel<<<(int)(W_ELS / 512), 512, 0, stream>>>(wih, whh, wb);
    gru_kernel<1><<<BB, 512, 0, stream>>>(x, is_init, wih, whh, bih, bhh, wb, out);
  } else {
    gru_kernel<0><<<BB, 512, 0, stream>>>(x, is_init, wih, whh, bih, bhh, nullptr, out);
  }
}

// Round 16
// 221.764 us; speedup vs baseline: 1.2370x; 1.2370x over previous
//
#include <hip/hip_runtime.h>
#include <cstdint>
#include <cstddef>

#define BB 256
#define TT 128
#define AA 4
#define II 128
#define HH 256
#define K3 768  // 3*H

typedef __attribute__((ext_vector_type(8))) short short8;
typedef __attribute__((ext_vector_type(4))) float f32x4;
typedef __attribute__((ext_vector_type(4))) unsigned short ushort4_t;

// workgroup barrier draining ONLY lgkmcnt (LDS), not vmcnt.
#define LGKM_BARRIER() asm volatile("s_waitcnt lgkmcnt(0)\n\ts_barrier" ::: "memory")

static __device__ __forceinline__ unsigned short f2bf(float f) {
  unsigned int b = __float_as_uint(f);
  return (unsigned short)((b + 0x7FFFu + ((b >> 16) & 1u)) >> 16);  // RNE
}
static __device__ __forceinline__ float bf2f(unsigned short u) {
  return __uint_as_float(((unsigned int)u) << 16);
}

// fp32 -> bf16 weight conversion into workspace (W_ih then W_hh, row-major)
__global__ void wconv_kernel(const float* __restrict__ wih,
                             const float* __restrict__ whh,
                             unsigned short* __restrict__ o) {
  int i = blockIdx.x * 512 + threadIdx.x;
  float v = (i < K3 * II) ? wih[i] : whh[i - K3 * II];
  o[i] = f2bf(v);
}

// ---------------- Phase A: gi = x * W_ih^T + b_ih (+ b_hh for r,z), bf16 ----
// Gate-split blocks (r14-verified). Block bid: rows (bid>>1)*64, gate half
// (bid&1)*384. Wave owns 3 tiles -> wf[3][4] = 48 persistent VGPRs, ~100
// total -> 2 blocks/CU / 4 waves/SIMD. Weights from bf16 ws (short8 loads).
__global__ __launch_bounds__(512, 4) void gi_kernel(
    const float* __restrict__ x,
    const float* __restrict__ bih_g,
    const float* __restrict__ bhh_g,
    const unsigned short* __restrict__ wb,   // W_ih bf16 at ws[0]
    unsigned short* __restrict__ gi) {
  __shared__ alignas(16) unsigned short xs[64][144];
  __shared__ alignas(16) unsigned short gst[16][408];
  __shared__ float bihs[384];

  const int tid = threadIdx.x;
  const int l = tid & 63, w = tid >> 6;
  const int c = l & 15, g = l >> 4;
  const int bid = blockIdx.x;
  const size_t m0 = (size_t)(bid >> 1) * 64;
  const int gh0 = (bid & 1) * 384;  // gate-half offset

  for (int i = tid; i < 384; i += 512) {
    int gg = gh0 + i;
    bihs[i] = bih_g[gg] + (gg < 2 * HH ? bhh_g[gg] : 0.f);
  }
  for (int i = tid; i < 64 * 128; i += 512) {
    int row = i >> 7, col = i & 127;
    xs[row][col] = f2bf(x[m0 * 128 + i]);
  }
  // persistent W_ih fragments: wave w owns gate rows gh0+48w .. +48 (3 tiles)
  short8 wf[3][4];
#pragma unroll
  for (int kt = 0; kt < 3; ++kt) {
    int row = gh0 + 48 * w + kt * 16 + c;
#pragma unroll
    for (int kk = 0; kk < 4; ++kk)
      wf[kt][kk] = *(const short8*)&wb[(size_t)row * II + kk * 32 + g * 8];
  }
  LGKM_BARRIER();

  for (int chunk = 0; chunk < 4; ++chunk) {
    short8 bx[4];
#pragma unroll
    for (int kk = 0; kk < 4; ++kk)
      bx[kk] = *(const short8*)&xs[chunk * 16 + c][kk * 32 + g * 8];
    f32x4 acc[3];
#pragma unroll
    for (int kt = 0; kt < 3; ++kt) acc[kt] = (f32x4){0.f, 0.f, 0.f, 0.f};
#pragma unroll
    for (int kt = 0; kt < 3; ++kt)
#pragma unroll
      for (int kk = 0; kk < 4; ++kk)
        acc[kt] = __builtin_amdgcn_mfma_f32_16x16x32_bf16(wf[kt][kk], bx[kk], acc[kt], 0, 0, 0);
#pragma unroll
    for (int kt = 0; kt < 3; ++kt) {
      int gate0 = 48 * w + kt * 16 + g * 4;  // local within half
      ushort4_t p;
#pragma unroll
      for (int r = 0; r < 4; ++r) p[r] = f2bf(acc[kt][r] + bihs[gate0 + r]);
      *(ushort4_t*)&gst[c][gate0] = p;
    }
    LGKM_BARRIER();
    // write 16 rows x 384 gates (48 short8 segs/row), coalesced
    for (int i = tid; i < 16 * 48; i += 512) {
      int row = i / 48, seg = i - row * 48;
      *(short8*)(gi + (m0 + chunk * 16 + row) * K3 + gh0 + seg * 8) =
          *(const short8*)&gst[row][seg * 8];
    }
    LGKM_BARRIER();
  }
}

// ---------------- Phase B: chunk-parallel recurrence (16 MFMA columns) -----
// Byte-identical to verified round 14 (weights hoisted before probe,
// even-step loop).
__global__ __launch_bounds__(512, 2) void rnn_kernel(
    const void* __restrict__ init_raw,
    const float* __restrict__ bhh_g,
    const unsigned short* __restrict__ wsb,  // ws bf16 base: [W_ih | W_hh]
    const unsigned short* __restrict__ gi,
    float* __restrict__ out) {
  extern __shared__ char smem[];
  unsigned short* wlN = (unsigned short*)smem;              // 131072 B (N frags)
  unsigned short* hflat = (unsigned short*)(smem + 131072); // 2 x 4096 ushorts
  unsigned char* mskL = (unsigned char*)(smem + 147456);    // 132 B
  int* bnd = (int*)(smem + 147592);                         // 5 ints
  int* detf = (int*)(smem + 147612);                        // 3 ints

  const int tid = threadIdx.x;
  const int b = blockIdx.x;
  const unsigned short* whh_b = wsb + K3 * II;
  const int l = tid & 63, w = tid >> 6;
  const int c = l & 15, g = l >> 4;

  if (tid < 3) detf[tid] = 0;

  // ---- persistent weight tiles FIRST (latency overlaps probe below) ----
  short8 wreg[4][8];
#pragma unroll
  for (int q = 0; q < 4; ++q) {
    int row = (q >> 1) * 256 + 32 * w + (q & 1) * 16 + c;
#pragma unroll
    for (int kk = 0; kk < 8; ++kk)
      wreg[q][kk] = *(const short8*)&whh_b[(size_t)row * HH + kk * 32 + g * 8];
  }
  // N0,N1 tiles -> LDS fragment order (verified layout)
  for (int f = tid; f < 8192; f += 512) {
    int w2 = f >> 10, n = (f >> 9) & 1, kk = (f >> 6) & 7, l2 = f & 63;
    int row = 512 + 32 * w2 + 16 * n + (l2 & 15);
    int col = kk * 32 + (l2 >> 4) * 8;
    *(short8*)(wlN + (size_t)f * 8) = *(const short8*)&whh_b[(size_t)row * HH + col];
  }
  for (int i = tid; i < 8192; i += 512) hflat[i] = 0;

  // ---- is_init layout probe (verified r1-r14 logic) ----
  {
    const unsigned int* wq = (const unsigned int*)init_raw;
    int notf = 0, gt1 = 0, oddnz = 0;
    for (int i = tid; i < (BB * TT / 4); i += 512) {
      unsigned int v = wq[i];
      notf |= (v != 0u && v != 0x3F800000u);
      gt1 |= (v > 1u);
      if (i & 1) oddnz |= (v != 0u);
    }
    if (notf) atomicOr(&detf[0], 1);
    if (gt1) atomicOr(&detf[1], 1);
    if (oddnz) atomicOr(&detf[2], 1);
  }
  __syncthreads();
  if (tid < TT) {
    int layout = (!detf[0]) ? 1 : (detf[1] ? 0 : (detf[2] ? 1 : 2));
    int e = b * TT + tid;
    unsigned int v;
    if (layout == 0)      v = ((const unsigned char*)init_raw)[e];
    else if (layout == 1) v = ((const unsigned int*)init_raw)[e];
    else                  v = ((const unsigned int*)init_raw)[2 * e];
    mskL[tid] = v ? 1 : 0;
  }
  if (tid == TT) mskL[TT] = 1;  // sentinel: t=128 "resets"
  __syncthreads();
  // chunk boundaries: b_q = first reset >= 32q (else 128)
  if (tid < 3) {
    int target = 32 * (tid + 1);
    int bb = TT;
    for (int t = target; t < TT; ++t)
      if (mskL[t]) { bb = t; break; }
    bnd[tid + 1] = bb;
  }
  if (tid == 3) { bnd[0] = 0; bnd[4] = TT; }
  __syncthreads();

  // per-lane column: chunk q = c>>2, agent a = c&3; units j0 = 32w+4g (+16)
  const int a = c & 3, q = c >> 2;
  const int j0 = 32 * w + g * 4;
  int tcur = bnd[q];
  int trem = bnd[q + 1] - tcur;
  int maxlen = bnd[1] - bnd[0];
  { int l1 = bnd[2] - bnd[1]; if (l1 > maxlen) maxlen = l1;
    int l2 = bnd[3] - bnd[2]; if (l2 > maxlen) maxlen = l2;
    int l3 = TT - bnd[3];     if (l3 > maxlen) maxlen = l3; }
  const int taddr = (tcur < TT) ? tcur : (TT - 1);
  const unsigned short* gp = gi + ((size_t)(b * TT + taddr) * AA + a) * K3 + j0;
  float* op = out + ((size_t)(b * TT + taddr) * AA + a) * HH + j0;
  f32x4 bn[2];
  bn[0] = *(const f32x4*)&bhh_g[2 * HH + j0];
  bn[1] = *(const f32x4*)&bhh_g[2 * HH + j0 + 16];
  float* hnp = out + (size_t)BB * TT * AA * HH + ((size_t)b * AA + a) * HH + j0;

  // hsb addressing: READ slot = kk*512 + l*8 (lane-contig 16B, conflict-free)
  // WRITE: w*512 + (g>>1)*128 + c*8 + (g&1)*4, hb1 at +256.
  const unsigned short* hrd = hflat + l * 8;                       // +P*4096+kk*512
  unsigned short* hw1 = hflat + w * 512 + (g >> 1) * 128 + c * 8 + (g & 1) * 4;
  const unsigned short* wlp = wlN + w * 8192 + l * 8;              // +n*4096+kk*512

  f32x4 hold[2];
  hold[0] = (f32x4){0.f, 0.f, 0.f, 0.f};
  hold[1] = (f32x4){0.f, 0.f, 0.f, 0.f};
  const f32x4 Z4 = {0.f, 0.f, 0.f, 0.f};

#define L2E 1.44269504088896f

#define STEP(P)                                                                   \
  do {                                                                            \
    ushort4_t gr0 = *(const ushort4_t*)(gp);                                      \
    ushort4_t gr1 = *(const ushort4_t*)(gp + 16);                                 \
    ushort4_t gz0 = *(const ushort4_t*)(gp + 256);                                \
    ushort4_t gz1 = *(const ushort4_t*)(gp + 272);                                \
    ushort4_t gn0 = *(const ushort4_t*)(gp + 512);                                \
    ushort4_t gn1 = *(const ushort4_t*)(gp + 528);                                \
    short8 bhf[8];                                                                \
    _Pragma("unroll") for (int kk = 0; kk < 8; ++kk)                              \
        bhf[kk] = *(const short8*)(hrd + (P) * 4096 + kk * 512);                  \
    f32x4 aR0 = __builtin_amdgcn_mfma_f32_16x16x32_bf16(wreg[0][0], bhf[0], Z4, 0, 0, 0); \
    f32x4 aR1 = __builtin_amdgcn_mfma_f32_16x16x32_bf16(wreg[1][0], bhf[0], Z4, 0, 0, 0); \
    f32x4 aZ0 = __builtin_amdgcn_mfma_f32_16x16x32_bf16(wreg[2][0], bhf[0], Z4, 0, 0, 0); \
    f32x4 aZ1 = __builtin_amdgcn_mfma_f32_16x16x32_bf16(wreg[3][0], bhf[0], Z4, 0, 0, 0); \
    f32x4 aN0 = __builtin_amdgcn_mfma_f32_16x16x32_bf16(*(const short8*)(wlp), bhf[0], Z4, 0, 0, 0); \
    f32x4 aN1 = __builtin_amdgcn_mfma_f32_16x16x32_bf16(*(const short8*)(wlp + 4096), bhf[0], Z4, 0, 0, 0); \
    _Pragma("unroll") for (int kk = 1; kk < 8; ++kk) {                            \
      aR0 = __builtin_amdgcn_mfma_f32_16x16x32_bf16(wreg[0][kk], bhf[kk], aR0, 0, 0, 0); \
      aR1 = __builtin_amdgcn_mfma_f32_16x16x32_bf16(wreg[1][kk], bhf[kk], aR1, 0, 0, 0); \
      aZ0 = __builtin_amdgcn_mfma_f32_16x16x32_bf16(wreg[2][kk], bhf[kk], aZ0, 0, 0, 0); \
      aZ1 = __builtin_amdgcn_mfma_f32_16x16x32_bf16(wreg[3][kk], bhf[kk], aZ1, 0, 0, 0); \
      aN0 = __builtin_amdgcn_mfma_f32_16x16x32_bf16(*(const short8*)(wlp + kk * 512), bhf[kk], aN0, 0, 0, 0); \
      aN1 = __builtin_amdgcn_mfma_f32_16x16x32_bf16(*(const short8*)(wlp + 4096 + kk * 512), bhf[kk], aN1, 0, 0, 0); \
    }                                                                             \
    f32x4 hnv0, hnv1;                                                             \
    ushort4_t hb0, hb1;                                                           \
    _Pragma("unroll") for (int r = 0; r < 4; ++r) {                               \
      const float pr = bf2f(gr0[r]) + aR0[r];                                     \
      const float pz = bf2f(gz0[r]) + aZ0[r];                                     \
      const float rs = __builtin_amdgcn_rcpf(1.f + __builtin_amdgcn_exp2f(-pr * L2E)); \
      const float zs = __builtin_amdgcn_rcpf(1.f + __builtin_amdgcn_exp2f(-pz * L2E)); \
      const float hn = aN0[r] + bn[0][r];                                         \
      const float pre = bf2f(gn0[r]) + rs * hn;                                   \
      const float nn = 1.f - 2.f * __builtin_amdgcn_rcpf(1.f + __builtin_amdgcn_exp2f(pre * (2.f * L2E))); \
      const float hv = fmaf(zs, hold[0][r] - nn, nn);                             \
      hnv0[r] = hv; hb0[r] = f2bf(hv);                                            \
    }                                                                             \
    _Pragma("unroll") for (int r = 0; r < 4; ++r) {                               \
      const float pr = bf2f(gr1[r]) + aR1[r];                                     \
      const float pz = bf2f(gz1[r]) + aZ1[r];                                     \
      const float rs = __builtin_amdgcn_rcpf(1.f + __builtin_amdgcn_exp2f(-pr * L2E)); \
      const float zs = __builtin_amdgcn_rcpf(1.f + __builtin_amdgcn_exp2f(-pz * L2E)); \
      const float hn = aN1[r] + bn[1][r];                                         \
      const float pre = bf2f(gn1[r]) + rs * hn;                                   \
      const float nn = 1.f - 2.f * __builtin_amdgcn_rcpf(1.f + __builtin_amdgcn_exp2f(pre * (2.f * L2E))); \
      const float hv = fmaf(zs, hold[1][r] - nn, nn);                             \
      hnv1[r] = hv; hb1[r] = f2bf(hv);                                            \
    }                                                                             \
    hold[0] = hnv0; hold[1] = hnv1;                                               \
    const bool active = (trem > 0);                                               \
    if (active) {                                                                 \
      *(f32x4*)op = hnv0;                                                         \
      *(f32x4*)(op + 16) = hnv1;                                                  \
      if (tcur == TT - 1) { *(f32x4*)hnp = hnv0; *(f32x4*)(hnp + 16) = hnv1; }    \
      tcur += 1; trem -= 1;                                                       \
      if (trem > 0) { gp += AA * K3; op += AA * HH; }                             \
    }                                                                             \
    const int mn = mskL[tcur];                                                    \
    if (mn) {                                                                     \
      hb0 = (ushort4_t)0; hb1 = (ushort4_t)0;                                     \
      hold[0] = Z4; hold[1] = Z4;                                                 \
    }                                                                             \
    *(ushort4_t*)(hw1 + (1 - (P)) * 4096) = hb0;                                  \
    *(ushort4_t*)(hw1 + 256 + (1 - (P)) * 4096) = hb1;                            \
    LGKM_BARRIER();                                                               \
  } while (0)

  const int nsteps = (maxlen + 1) & ~1;
  for (int i = 0; i < nsteps; i += 2) {
    STEP(0);
    STEP(1);
  }
#undef STEP
}

// ---------------- Fallback: round-1 kernel (known-pass) ----------------
template <int WSW>
__global__ __launch_bounds__(512, 2) void gru_kernel(
    const float* __restrict__ x,
    const void* __restrict__ init_raw,
    const float* __restrict__ wih_f,
    const float* __restrict__ whh_f,
    const float* __restrict__ bih_g,
    const float* __restrict__ bhh_g,
    const unsigned short* __restrict__ wb,
    float* __restrict__ out) {
  __shared__ alignas(16) unsigned short xs[AA][II + 8];
  __shared__ alignas(16) unsigned short hsb[AA][HH + 8];
  __shared__ float hs32[AA][HH];
  __shared__ float gi_s[K3][5];
  __shared__ float gh_s[K3][5];
  __shared__ float bihs[K3];
  __shared__ float bhhs[K3];
  __shared__ unsigned char msk[TT];
  __shared__ int detf[3];

  const int tid = threadIdx.x;
  const int b = blockIdx.x;

  if (tid < 3) detf[tid] = 0;
  for (int i = tid; i < K3; i += 512) { bihs[i] = bih_g[i]; bhhs[i] = bhh_g[i]; }
  for (int i = tid; i < AA * HH; i += 512) {
    hs32[i >> 8][i & 255] = 0.f;
    hsb[i >> 8][i & 255] = 0;
  }
  __syncthreads();
  {
    const unsigned int* wq = (const unsigned int*)init_raw;
    int notf = 0, gt1 = 0, oddnz = 0;
    for (int i = tid; i < (BB * TT / 4); i += 512) {
      unsigned int v = wq[i];
      notf |= (v != 0u && v != 0x3F800000u);
      gt1 |= (v > 1u);
      if (i & 1) oddnz |= (v != 0u);
    }
    if (notf) atomicOr(&detf[0], 1);
    if (gt1) atomicOr(&detf[1], 1);
    if (oddnz) atomicOr(&detf[2], 1);
  }
  __syncthreads();
  if (tid < TT) {
    int layout = (!detf[0]) ? 1 : (detf[1] ? 0 : (detf[2] ? 1 : 2));
    int e = b * TT + tid;
    unsigned int v;
    if (layout == 0)      v = ((const unsigned char*)init_raw)[e];
    else if (layout == 1) v = ((const unsigned int*)init_raw)[e];
    else                  v = ((const unsigned int*)init_raw)[2 * e];
    msk[tid] = v ? 1 : 0;
  }
  __syncthreads();

  const int l = tid & 63;
  const int w = tid >> 6;
  const int c = l & 15;
  const int g = l >> 4;
  const bool act = (c < AA);
  const int xa = tid >> 7, xi = tid & 127;
  const float* xrow = x + (size_t)b * TT * AA * II;
  const unsigned short* wihb = wb;
  const unsigned short* whhb = wb + K3 * II;

  for (int t = 0; t < TT; ++t) {
    xs[xa][xi] = f2bf(xrow[(size_t)t * (AA * II) + tid]);
    if (msk[t]) {
      for (int i = tid; i < AA * HH; i += 512) {
        hs32[i >> 8][i & 255] = 0.f;
        hsb[i >> 8][i & 255] = 0;
      }
    }
    __syncthreads();

    short8 bx[4], bh[8];
    if (act) {
#pragma unroll
      for (int kk = 0; kk < 4; ++kk) bx[kk] = *(const short8*)&xs[c][kk * 32 + g * 8];
#pragma unroll
      for (int kk = 0; kk < 8; ++kk) bh[kk] = *(const short8*)&hsb[c][kk * 32 + g * 8];
    } else {
#pragma unroll
      for (int kk = 0; kk < 4; ++kk) bx[kk] = (short8)0;
#pragma unroll
      for (int kk = 0; kk < 8; ++kk) bh[kk] = (short8)0;
    }

#pragma unroll
    for (int kt = 0; kt < 6; ++kt) {
      const int ar = w * 96 + kt * 16 + c;
      f32x4 acc = {0.f, 0.f, 0.f, 0.f};
#pragma unroll
      for (int kk = 0; kk < 4; ++kk) {
        short8 aw;
        if (WSW) {
          aw = *(const short8*)&wihb[(size_t)ar * II + kk * 32 + g * 8];
        } else {
          const float* p = &wih_f[(size_t)ar * II + kk * 32 + g * 8];
#pragma unroll
          for (int e = 0; e < 8; ++e) aw[e] = (short)f2bf(p[e]);
        }
        acc = __builtin_amdgcn_mfma_f32_16x16x32_bf16(aw, bx[kk], acc, 0, 0, 0);
      }
      if (act) {
        const int dr = w * 96 + kt * 16 + g * 4;
#pragma unroll
        for (int r = 0; r < 4; ++r) gi_s[dr + r][c] = acc[r];
      }
    }

#pragma unroll
    for (int kt = 0; kt < 6; ++kt) {
      const int ar = w * 96 + kt * 16 + c;
      f32x4 acc = {0.f, 0.f, 0.f, 0.f};
#pragma unroll
      for (int kk = 0; kk < 8; ++kk) {
        short8 aw;
        if (WSW) {
          aw = *(const short8*)&whhb[(size_t)ar * HH + kk * 32 + g * 8];
        } else {
          const float* p = &whh_f[(size_t)ar * HH + kk * 32 + g * 8];
#pragma unroll
          for (int e = 0; e < 8; ++e) aw[e] = (short)f2bf(p[e]);
        }
        acc = __builtin_amdgcn_mfma_f32_16x16x32_bf16(aw, bh[kk], acc, 0, 0, 0);
      }
      if (act) {
        const int dr = w * 96 + kt * 16 + g * 4;
#pragma unroll
        for (int r = 0; r < 4; ++r) gh_s[dr + r][c] = acc[r];
      }
    }
    __syncthreads();

#pragma unroll
    for (int it = 0; it < 2; ++it) {
      const int idx = it * 512 + tid;
      const int a = idx >> 8, j = idx & 255;
      const float ir = gi_s[j][a] + bihs[j];
      const float iz = gi_s[HH + j][a] + bihs[HH + j];
      const float inn = gi_s[2 * HH + j][a] + bihs[2 * HH + j];
      const float hr = gh_s[j][a] + bhhs[j];
      const float hz = gh_s[HH + j][a] + bhhs[HH + j];
      const float hn = gh_s[2 * HH + j][a] + bhhs[2 * HH + j];
      const float r = 1.f / (1.f + __expf(-(ir + hr)));
      const float z = 1.f / (1.f + __expf(-(iz + hz)));
      const float pre = inn + r * hn;
      const float ea = __expf(-2.f * fabsf(pre));
      float n = (1.f - ea) / (1.f + ea);
      n = (pre < 0.f) ? -n : n;
      const float hold = hs32[a][j];
      const float hnew = (1.f - z) * n + z * hold;
      hs32[a][j] = hnew;
      hsb[a][j] = f2bf(hnew);
      out[(((size_t)b * TT + t) * AA + a) * HH + j] = hnew;
      if (t == TT - 1)
        out[(size_t)BB * TT * AA * HH + ((size_t)b * AA + a) * HH + j] = hnew;
    }
    __syncthreads();
  }
}

extern "C" void kernel_launch(void* const* d_in, const int* in_sizes, int n_in,
                              void* d_out, int out_size, void* d_ws, size_t ws_size,
                              hipStream_t stream) {
  (void)in_sizes; (void)n_in; (void)out_size;
  const float* x = (const float*)d_in[0];
  const void* is_init = d_in[1];
  const float* wih = (const float*)d_in[2];
  const float* whh = (const float*)d_in[3];
  const float* bih = (const float*)d_in[4];
  const float* bhh = (const float*)d_in[5];
  float* out = (float*)d_out;

  const size_t W_ELS = (size_t)(K3 * II + K3 * HH);        // 294,912
  const size_t W_BYTES = W_ELS * 2;                        // 589,824
  const size_t GI_BYTES = (size_t)BB * TT * AA * K3 * 2;   // 201,326,592
  const int SMEM = 147632;

  if (ws_size >= W_BYTES + GI_BYTES) {
    hipError_t e = hipFuncSetAttribute(
        (const void*)rnn_kernel, hipFuncAttributeMaxDynamicSharedMemorySize, SMEM);
    if (e == hipSuccess) {
      unsigned short* wb = (unsigned short*)d_ws;
      unsigned short* gi = wb + W_ELS;
      wconv_kernel<<<(int)(W_ELS / 512), 512, 0, stream>>>(wih, whh, wb);
      gi_kernel<<<4096, 512, 0, stream>>>(x, bih, bhh, wb, gi);
      rnn_kernel<<<BB, 512, SMEM, stream>>>(is_init, bhh, wb, gi, out);
      return;
    }
  }
  // fallback (round-1 verified path)
  if (ws_size >= W_BYTES) {
    unsigned short* wb = (unsigned short*)d_ws;
    wconv_kernel<<<(int)(W_ELS / 512), 512, 0, stream>>>(wih, whh, wb);
    gru_kernel<1><<<BB, 512, 0, stream>>>(x, is_init, wih, whh, bih, bhh, wb, out);
  } else {
    gru_kernel<0><<<BB, 512, 0, stream>>>(x, is_init, wih, whh, bih, bhh, nullptr, out);
  }
}